// Round 8
// baseline (170.617 us; speedup 1.0000x reference)
//
#include <hip/hip_runtime.h>
#include <hip/hip_bf16.h>
#include <stdint.h>

#define BATCH 4
#define SLEN  2048
#define DDIM  1024
#define NEGV  -1e9f

typedef unsigned short u16;
typedef __attribute__((ext_vector_type(8))) short bf16x8;
typedef __attribute__((ext_vector_type(4))) float f32x4;

__device__ __forceinline__ float bf2f(u16 u) {
  union { unsigned u; float f; } c; c.u = ((unsigned)u) << 16; return c.f;
}
__device__ __forceinline__ u16 f2bf(float f) {
  union { float f; unsigned u; } c; c.f = f;
  unsigned r = c.u + 0x7fffu + ((c.u >> 16) & 1u);
  return (u16)(r >> 16);
}

__device__ __forceinline__ float wred_sum(float v) {
#pragma unroll
  for (int o = 32; o > 0; o >>= 1) v += __shfl_xor(v, o, 64);
  return v;
}
__device__ __forceinline__ float wred_max(float v) {
#pragma unroll
  for (int o = 32; o > 0; o >>= 1) v = fmaxf(v, __shfl_xor(v, o, 64));
  return v;
}

// async global -> LDS, 16B per lane. LDS dest must be wave-uniform base + lane*16.
__device__ __forceinline__ void async_copy16(u16* lds_p, const u16* g) {
  __builtin_amdgcn_global_load_lds((const __attribute__((address_space(1))) void*)g,
                                   (__attribute__((address_space(3))) void*)lds_p,
                                   16, 0, 0);
}

// ---------------------------------------------------------------- kernel 1
// LayerNorm rows of src and trg -> bf16. grid (B*S, 2), block 256.
__global__ __launch_bounds__(256)
void ln_to_bf16(const float* __restrict__ src, const float* __restrict__ trg,
                const float* __restrict__ gamma, const float* __restrict__ beta,
                u16* __restrict__ src_n, u16* __restrict__ trg_n) {
  const int row = blockIdx.x;
  const float* in = (blockIdx.y == 0 ? src : trg) + (size_t)row * DDIM;
  u16* out = (blockIdx.y == 0 ? src_n : trg_n) + (size_t)row * DDIM;
  const int tid = threadIdx.x;
  float4 x = ((const float4*)in)[tid];
  float s  = x.x + x.y + x.z + x.w;
  float s2 = x.x * x.x + x.y * x.y + x.z * x.z + x.w * x.w;
  s = wred_sum(s); s2 = wred_sum(s2);
  __shared__ float rs_[4], rs2_[4];
  const int wid = tid >> 6, lane = tid & 63;
  if (lane == 0) { rs_[wid] = s; rs2_[wid] = s2; }
  __syncthreads();
  s  = rs_[0] + rs_[1] + rs_[2] + rs_[3];
  s2 = rs2_[0] + rs2_[1] + rs2_[2] + rs2_[3];
  const float mu = s * (1.0f / DDIM);
  const float var = s2 * (1.0f / DDIM) - mu * mu;
  const float rstd = rsqrtf(var + 1e-5f);
  float4 g = ((const float4*)gamma)[tid];
  float4 be = ((const float4*)beta)[tid];
  ushort4 o;
  o.x = f2bf((x.x - mu) * rstd * g.x + be.x);
  o.y = f2bf((x.y - mu) * rstd * g.y + be.y);
  o.z = f2bf((x.z - mu) * rstd * g.z + be.z);
  o.w = f2bf((x.w - mu) * rstd * g.w + be.w);
  ((ushort4*)out)[tid] = o;
}

// ---------------------------------------------------------------- kernel 2
// bf16 transpose [B][S][D] -> [B][D][S]. 64x64 tiles, grid (S/64, D/64, B).
__global__ __launch_bounds__(256)
void transpose_bf16(const u16* __restrict__ in, u16* __restrict__ out) {
  __shared__ u16 t[64][65];
  const int b = blockIdx.z;
  const int s0 = blockIdx.x * 64, d0 = blockIdx.y * 64;
  const u16* ib = in + (size_t)b * SLEN * DDIM;
  u16* ob = out + (size_t)b * DDIM * SLEN;
  const int tid = threadIdx.x;
  const int c4 = (tid & 15) * 4, r = tid >> 4;
#pragma unroll
  for (int it = 0; it < 4; ++it) {
    int rr = r + it * 16;
    ushort4 v = *(const ushort4*)&ib[(size_t)(s0 + rr) * DDIM + d0 + c4];
    t[rr][c4 + 0] = v.x; t[rr][c4 + 1] = v.y; t[rr][c4 + 2] = v.z; t[rr][c4 + 3] = v.w;
  }
  __syncthreads();
#pragma unroll
  for (int it = 0; it < 4; ++it) {
    int dd = r + it * 16;
    ushort4 v;
    v.x = t[c4 + 0][dd]; v.y = t[c4 + 1][dd]; v.z = t[c4 + 2][dd]; v.w = t[c4 + 3][dd];
    *(ushort4*)&ob[(size_t)(d0 + dd) * SLEN + s0 + c4] = v;
  }
}

// ---------------------------------------------------------------- kernel 3/5
// NT GEMM: C[M][N] = A[M][K] * B[N][K]^T, bf16 in, fp32 acc.
// 128x128 tile, BK=64, 4 waves (2x2), 16x16x32 MFMA.
// 2-PHASE double-buffered staging (T3 minimum recipe): issue next K-tile's
// global_load_lds BEFORE computing current tile; ONE __syncthreads per step
// (its vmcnt(0) drain is covered by the ds_read+MFMA work preceding it).
// LDS [2][128][64] bf16 per operand = 64 KiB -> 2 blocks/CU.
// G4 swizzle (128B rows): LDS (r,c) holds global (r, c ^ ((r&7)<<4)) bytes;
// inverse-swizzled global source (linear LDS dest, rule 21); read-side XOR
// (l15&7)<<4 -> 8x16B slots, 2 lanes/slot = conflict-free (m136).
// 1-D grid + bijective XCD chunk swizzle (nwg%8==0) for L2 panel reuse.
// MODE 0: scores epilogue (scale 1/D, masks, bf16 out); MODE 1: +residual fp32.
template <int MODE>
__global__ __launch_bounds__(256, 2)
void gemm_nt(const u16* __restrict__ Aall, const u16* __restrict__ Ball,
             int M, int N, int K,
             const float* __restrict__ kpm, const float* __restrict__ mm,
             u16* __restrict__ outb,
             const float* __restrict__ resid, float* __restrict__ outf) {
  // ----- XCD-chunked swizzle over the flat grid
  const int nwg = gridDim.x;
  const int cpx = nwg >> 3;
  const int bid = blockIdx.x;
  const int swz = (bid & 7) * cpx + (bid >> 3);
  const int ntx = N >> 7, nty = M >> 7;
  const int b = swz / (ntx * nty);
  const int rem = swz - b * (ntx * nty);
  const int mBase = (rem / ntx) * 128, nBase = (rem % ntx) * 128;

  const u16* A = Aall + (size_t)b * M * K;
  const u16* B = Ball + (size_t)b * N * K;
  const int tid = threadIdx.x, lane = tid & 63, wid = tid >> 6;
  const int wm = (wid >> 1) * 64, wn = (wid & 1) * 64;
  __shared__ __align__(16) u16 As[2][128 * 64];
  __shared__ __align__(16) u16 Bs[2][128 * 64];
  f32x4 acc[4][4];
  const f32x4 zz = {0.0f, 0.0f, 0.0f, 0.0f};
#pragma unroll
  for (int i = 0; i < 4; ++i)
#pragma unroll
    for (int j = 0; j < 4; ++j) acc[i][j] = zz;

  const int l15 = lane & 15, lk = lane >> 4;
  const int swl = (l15 & 7) << 4;   // read-side swizzle XOR (bytes), lane-constant

  auto STAGE = [&](int buf, int k0) {
#pragma unroll
    for (int c = 0; c < 4; ++c) {
      const int q = c * 4096 + tid * 16;              // linear byte off in tile
      const int row = q >> 7;
      const int scol = (q & 127) ^ ((row & 7) << 4);  // inverse-swizzled src col
      async_copy16(&As[buf][q >> 1], &A[(size_t)(mBase + row) * K + k0 + (scol >> 1)]);
    }
#pragma unroll
    for (int c = 0; c < 4; ++c) {
      const int q = c * 4096 + tid * 16;
      const int row = q >> 7;
      const int scol = (q & 127) ^ ((row & 7) << 4);
      async_copy16(&Bs[buf][q >> 1], &B[(size_t)(nBase + row) * K + k0 + (scol >> 1)]);
    }
  };

  const int NTt = K >> 6;
  // prologue: tile 0 resident
  STAGE(0, 0);
  __syncthreads();

  for (int T = 0; T < NTt; ++T) {
    const int cur = T & 1;
    if (T + 1 < NTt) STAGE(cur ^ 1, (T + 1) * 64);   // issue next-tile loads FIRST

    // ---- compute current tile: 2 k-slices x 16 MFMA
#pragma unroll
    for (int kk = 0; kk < 2; ++kk) {
      const int cb = (kk * 64 + lk * 16) ^ swl;      // swizzled byte col
      bf16x8 af[4], bfr[4];
#pragma unroll
      for (int i = 0; i < 4; ++i)
        af[i] = *(const bf16x8*)&As[cur][((wm + i * 16 + l15) * 128 + cb) >> 1];
#pragma unroll
      for (int j = 0; j < 4; ++j)
        bfr[j] = *(const bf16x8*)&Bs[cur][((wn + j * 16 + l15) * 128 + cb) >> 1];
#pragma unroll
      for (int i = 0; i < 4; ++i)
#pragma unroll
        for (int j = 0; j < 4; ++j)
          acc[i][j] = __builtin_amdgcn_mfma_f32_16x16x32_bf16(af[i], bfr[j], acc[i][j], 0, 0, 0);
    }
    // one barrier per step: drains vmcnt (next tile resident) and publishes
    // that all waves finished reading buf `cur` before it is re-staged.
    __syncthreads();
  }

  // epilogue: C element [r0+i*16+t][c0+j*16]; lane: col=lane&15, rows=(lane>>4)*4+t
  const int r0 = mBase + wm + lk * 4;
  const int c0 = nBase + wn + l15;
#pragma unroll
  for (int i = 0; i < 4; ++i) {
#pragma unroll
    for (int j = 0; j < 4; ++j) {
      const int col = c0 + j * 16;
      float kp = (MODE == 0) ? kpm[b * SLEN + col] : 0.0f;
#pragma unroll
      for (int t = 0; t < 4; ++t) {
        const int row = r0 + i * 16 + t;
        if (MODE == 0) {
          float sc = acc[i][j][t] * (1.0f / DDIM);
          if (kp == 0.0f || mm[(size_t)row * SLEN + col] == 0.0f) sc = NEGV;
          outb[(size_t)b * M * N + (size_t)row * N + col] = f2bf(sc);
        } else {
          const size_t idx = (size_t)b * M * N + (size_t)row * N + col;
          outf[idx] = acc[i][j][t] + resid[idx];
        }
      }
    }
  }
}

// ---------------------------------------------------------------- kernel 4
// Row softmax over S=2048 bf16 values, in place. grid B*S, block 256.
__global__ __launch_bounds__(256)
void softmax_rows(u16* __restrict__ sc) {
  u16* p = sc + (size_t)blockIdx.x * SLEN;
  const int tid = threadIdx.x;
  uint4 raw = ((const uint4*)p)[tid];
  u16* rp = (u16*)&raw;
  float v[8];
#pragma unroll
  for (int i = 0; i < 8; ++i) v[i] = bf2f(rp[i]);
  float mx = v[0];
#pragma unroll
  for (int i = 1; i < 8; ++i) mx = fmaxf(mx, v[i]);
  mx = wred_max(mx);
  __shared__ float redm[4], reds[4];
  const int wid = tid >> 6, lane = tid & 63;
  if (lane == 0) redm[wid] = mx;
  __syncthreads();
  mx = fmaxf(fmaxf(redm[0], redm[1]), fmaxf(redm[2], redm[3]));
  float e[8], s = 0.0f;
#pragma unroll
  for (int i = 0; i < 8; ++i) { e[i] = __expf(v[i] - mx); s += e[i]; }
  s = wred_sum(s);
  if (lane == 0) reds[wid] = s;
  __syncthreads();
  s = reds[0] + reds[1] + reds[2] + reds[3];
  const float inv = 1.0f / s;
#pragma unroll
  for (int i = 0; i < 8; ++i) rp[i] = f2bf(e[i] * inv);
  ((uint4*)p)[tid] = raw;
}

// ---------------------------------------------------------------- kernel 6
// Final LayerNorm, fp32 in-place on d_out. grid B*S, block 256.
__global__ __launch_bounds__(256)
void ln_f32_inplace(float* __restrict__ x, const float* __restrict__ gamma,
                    const float* __restrict__ beta) {
  float* p = x + (size_t)blockIdx.x * DDIM;
  const int tid = threadIdx.x;
  float4 v = ((const float4*)p)[tid];
  float s  = v.x + v.y + v.z + v.w;
  float s2 = v.x * v.x + v.y * v.y + v.z * v.z + v.w * v.w;
  s = wred_sum(s); s2 = wred_sum(s2);
  __shared__ float rs_[4], rs2_[4];
  const int wid = tid >> 6, lane = tid & 63;
  if (lane == 0) { rs_[wid] = s; rs2_[wid] = s2; }
  __syncthreads();
  s  = rs_[0] + rs_[1] + rs_[2] + rs_[3];
  s2 = rs2_[0] + rs2_[1] + rs2_[2] + rs2_[3];
  const float mu = s * (1.0f / DDIM);
  const float var = s2 * (1.0f / DDIM) - mu * mu;
  const float rstd = rsqrtf(var + 1e-5f);
  float4 g = ((const float4*)gamma)[tid];
  float4 be = ((const float4*)beta)[tid];
  float4 o;
  o.x = (v.x - mu) * rstd * g.x + be.x;
  o.y = (v.y - mu) * rstd * g.y + be.y;
  o.z = (v.z - mu) * rstd * g.z + be.z;
  o.w = (v.w - mu) * rstd * g.w + be.w;
  ((float4*)p)[tid] = o;
}

extern "C" void kernel_launch(void* const* d_in, const int* in_sizes, int n_in,
                              void* d_out, int out_size, void* d_ws, size_t ws_size,
                              hipStream_t stream) {
  const float* src   = (const float*)d_in[0];
  const float* trg   = (const float*)d_in[1];
  const float* kpm   = (const float*)d_in[2];
  const float* mm    = (const float*)d_in[3];
  const float* gamma = (const float*)d_in[4];
  const float* beta  = (const float*)d_in[5];
  float* out = (float*)d_out;
  char* ws = (char*)d_ws;

  const size_t MB = 1024 * 1024;
  u16* src_n  = (u16*)(ws);                 // 16 MB  [B][S][D] bf16
  u16* trg_n  = (u16*)(ws + 16 * MB);       // 16 MB  [B][S][D] bf16
  u16* src_nT = (u16*)(ws + 32 * MB);       // 16 MB  [B][D][S] bf16
  u16* scores = (u16*)(ws + 48 * MB);       // 32 MB  [B][S][S] bf16

  ln_to_bf16<<<dim3(BATCH * SLEN, 2), 256, 0, stream>>>(src, trg, gamma, beta, src_n, trg_n);
  transpose_bf16<<<dim3(SLEN / 64, DDIM / 64, BATCH), 256, 0, stream>>>(src_n, src_nT);
  // scores: M=N=2048, K=1024 -> 16x16 tiles x 4 batches = 1024 blocks (flat)
  gemm_nt<0><<<dim3(BATCH * (SLEN / 128) * (SLEN / 128)), 256, 0, stream>>>(
      trg_n, src_n, SLEN, SLEN, DDIM, kpm, mm, scores, nullptr, nullptr);
  softmax_rows<<<dim3(BATCH * SLEN), 256, 0, stream>>>(scores);
  // PV: M=2048, N=1024, K=2048 -> 16x8 tiles x 4 batches = 512 blocks (flat)
  gemm_nt<1><<<dim3(BATCH * (SLEN / 128) * (DDIM / 128)), 256, 0, stream>>>(
      scores, src_nT, SLEN, DDIM, SLEN, nullptr, nullptr, nullptr, src, out);
  ln_f32_inplace<<<dim3(BATCH * SLEN), 256, 0, stream>>>(out, gamma, beta);
}

// Round 9
// 161.220 us; speedup vs baseline: 1.0583x; 1.0583x over previous
//
#include <hip/hip_runtime.h>
#include <hip/hip_bf16.h>
#include <stdint.h>

#define BATCH 4
#define SLEN  2048
#define DDIM  1024
#define NEGV  -1e9f

typedef unsigned short u16;
typedef __attribute__((ext_vector_type(8))) short bf16x8;
typedef __attribute__((ext_vector_type(4))) float f32x4;

__device__ __forceinline__ float bf2f(u16 u) {
  union { unsigned u; float f; } c; c.u = ((unsigned)u) << 16; return c.f;
}
__device__ __forceinline__ u16 f2bf(float f) {
  union { float f; unsigned u; } c; c.f = f;
  unsigned r = c.u + 0x7fffu + ((c.u >> 16) & 1u);
  return (u16)(r >> 16);
}

__device__ __forceinline__ float wred_sum(float v) {
#pragma unroll
  for (int o = 32; o > 0; o >>= 1) v += __shfl_xor(v, o, 64);
  return v;
}
__device__ __forceinline__ float wred_max(float v) {
#pragma unroll
  for (int o = 32; o > 0; o >>= 1) v = fmaxf(v, __shfl_xor(v, o, 64));
  return v;
}

// async global -> LDS, 16B per lane. LDS dest must be wave-uniform base + lane*16.
__device__ __forceinline__ void async_copy16(u16* lds_p, const u16* g) {
  __builtin_amdgcn_global_load_lds((const __attribute__((address_space(1))) void*)g,
                                   (__attribute__((address_space(3))) void*)lds_p,
                                   16, 0, 0);
}

// ---------------------------------------------------------------- kernel 1
// LayerNorm rows of src and trg -> bf16. grid (B*S, 2), block 256.
__global__ __launch_bounds__(256)
void ln_to_bf16(const float* __restrict__ src, const float* __restrict__ trg,
                const float* __restrict__ gamma, const float* __restrict__ beta,
                u16* __restrict__ src_n, u16* __restrict__ trg_n) {
  const int row = blockIdx.x;
  const float* in = (blockIdx.y == 0 ? src : trg) + (size_t)row * DDIM;
  u16* out = (blockIdx.y == 0 ? src_n : trg_n) + (size_t)row * DDIM;
  const int tid = threadIdx.x;
  float4 x = ((const float4*)in)[tid];
  float s  = x.x + x.y + x.z + x.w;
  float s2 = x.x * x.x + x.y * x.y + x.z * x.z + x.w * x.w;
  s = wred_sum(s); s2 = wred_sum(s2);
  __shared__ float rs_[4], rs2_[4];
  const int wid = tid >> 6, lane = tid & 63;
  if (lane == 0) { rs_[wid] = s; rs2_[wid] = s2; }
  __syncthreads();
  s  = rs_[0] + rs_[1] + rs_[2] + rs_[3];
  s2 = rs2_[0] + rs2_[1] + rs2_[2] + rs2_[3];
  const float mu = s * (1.0f / DDIM);
  const float var = s2 * (1.0f / DDIM) - mu * mu;
  const float rstd = rsqrtf(var + 1e-5f);
  float4 g = ((const float4*)gamma)[tid];
  float4 be = ((const float4*)beta)[tid];
  ushort4 o;
  o.x = f2bf((x.x - mu) * rstd * g.x + be.x);
  o.y = f2bf((x.y - mu) * rstd * g.y + be.y);
  o.z = f2bf((x.z - mu) * rstd * g.z + be.z);
  o.w = f2bf((x.w - mu) * rstd * g.w + be.w);
  ((ushort4*)out)[tid] = o;
}

// ---------------------------------------------------------------- kernel 2
// bf16 transpose [B][S][D] -> [B][D][S]. 64x64 tiles, grid (S/64, D/64, B).
__global__ __launch_bounds__(256)
void transpose_bf16(const u16* __restrict__ in, u16* __restrict__ out) {
  __shared__ u16 t[64][65];
  const int b = blockIdx.z;
  const int s0 = blockIdx.x * 64, d0 = blockIdx.y * 64;
  const u16* ib = in + (size_t)b * SLEN * DDIM;
  u16* ob = out + (size_t)b * DDIM * SLEN;
  const int tid = threadIdx.x;
  const int c4 = (tid & 15) * 4, r = tid >> 4;
#pragma unroll
  for (int it = 0; it < 4; ++it) {
    int rr = r + it * 16;
    ushort4 v = *(const ushort4*)&ib[(size_t)(s0 + rr) * DDIM + d0 + c4];
    t[rr][c4 + 0] = v.x; t[rr][c4 + 1] = v.y; t[rr][c4 + 2] = v.z; t[rr][c4 + 3] = v.w;
  }
  __syncthreads();
#pragma unroll
  for (int it = 0; it < 4; ++it) {
    int dd = r + it * 16;
    ushort4 v;
    v.x = t[c4 + 0][dd]; v.y = t[c4 + 1][dd]; v.z = t[c4 + 2][dd]; v.w = t[c4 + 3][dd];
    *(ushort4*)&ob[(size_t)(d0 + dd) * SLEN + s0 + c4] = v;
  }
}

// ---------------------------------------------------------------- kernel 3/5
// NT GEMM: C[M][N] = A[M][K] * B[N][K]^T, bf16 in, fp32 acc.
// 128x64 tile, BK=64, 4 waves (2M x 2N), wave-tile 64x32, 16x16x32 MFMA.
// Proven R6 2-barrier loop (stage -> sync -> MFMA -> sync). LDS 24 KiB
// single-buffered -> 6 blocks/CU (24 waves): small tiles give 2048/1024
// blocks so CUs run multiple ROUNDS -> refill desynchronization (one
// block's epilogue overlaps others' main loops; breaks the phase-locked
// barrier stalls seen at 4-blocks/CU with grid==capacity).
// G4 swizzle (128B rows): LDS (r,c) holds global (r, c ^ ((r&7)<<4)) bytes;
// inverse-swizzled global source (linear LDS dest, rule 21); read-side XOR
// (l15&7)<<4 -> 8x16B slots, 2 lanes/slot = conflict-free (m136).
// 1-D grid + bijective XCD chunk swizzle (nwg%8==0) for A-panel L2 reuse.
// MODE 0: scores epilogue (scale 1/D, masks, bf16 out); MODE 1: +residual fp32.
template <int MODE>
__global__ __launch_bounds__(256, 6)
void gemm_nt(const u16* __restrict__ Aall, const u16* __restrict__ Ball,
             int M, int N, int K,
             const float* __restrict__ kpm, const float* __restrict__ mm,
             u16* __restrict__ outb,
             const float* __restrict__ resid, float* __restrict__ outf) {
  // ----- XCD-chunked swizzle over the flat grid
  const int nwg = gridDim.x;
  const int cpx = nwg >> 3;
  const int bid = blockIdx.x;
  const int swz = (bid & 7) * cpx + (bid >> 3);
  const int ntx = N >> 6, nty = M >> 7;
  const int b = swz / (ntx * nty);
  const int rem = swz - b * (ntx * nty);
  const int mBase = (rem / ntx) * 128, nBase = (rem % ntx) * 64;

  const u16* A = Aall + (size_t)b * M * K;
  const u16* B = Ball + (size_t)b * N * K;
  const int tid = threadIdx.x, lane = tid & 63, wid = tid >> 6;
  const int wm = (wid >> 1) * 64, wn = (wid & 1) * 32;
  __shared__ __align__(16) u16 As[128 * 64];   // 16 KiB
  __shared__ __align__(16) u16 Bs[64 * 64];    //  8 KiB
  f32x4 acc[4][2];
  const f32x4 zz = {0.0f, 0.0f, 0.0f, 0.0f};
#pragma unroll
  for (int i = 0; i < 4; ++i)
#pragma unroll
    for (int j = 0; j < 2; ++j) acc[i][j] = zz;

  const int l15 = lane & 15, lk = lane >> 4;
  const int swl = (l15 & 7) << 4;   // read-side swizzle XOR (bytes), lane-constant

  for (int k0 = 0; k0 < K; k0 += 64) {
    // ---- stage A 128x64 (4 chunks) + B 64x64 (2 chunks), 16B/lane
#pragma unroll
    for (int c = 0; c < 4; ++c) {
      const int q = c * 4096 + tid * 16;              // linear byte off in tile
      const int row = q >> 7;
      const int scol = (q & 127) ^ ((row & 7) << 4);  // inverse-swizzled src col
      async_copy16(&As[q >> 1], &A[(size_t)(mBase + row) * K + k0 + (scol >> 1)]);
    }
#pragma unroll
    for (int c = 0; c < 2; ++c) {
      const int q = c * 4096 + tid * 16;
      const int row = q >> 7;
      const int scol = (q & 127) ^ ((row & 7) << 4);
      async_copy16(&Bs[q >> 1], &B[(size_t)(nBase + row) * K + k0 + (scol >> 1)]);
    }
    __syncthreads();   // drains vmcnt -> tiles resident

    // ---- 2 k-slices x 8 MFMA
#pragma unroll
    for (int kk = 0; kk < 2; ++kk) {
      const int cb = (kk * 64 + lk * 16) ^ swl;       // swizzled byte col
      bf16x8 af[4], bfr[2];
#pragma unroll
      for (int i = 0; i < 4; ++i)
        af[i] = *(const bf16x8*)&As[((wm + i * 16 + l15) * 128 + cb) >> 1];
#pragma unroll
      for (int j = 0; j < 2; ++j)
        bfr[j] = *(const bf16x8*)&Bs[((wn + j * 16 + l15) * 128 + cb) >> 1];
#pragma unroll
      for (int i = 0; i < 4; ++i)
#pragma unroll
        for (int j = 0; j < 2; ++j)
          acc[i][j] = __builtin_amdgcn_mfma_f32_16x16x32_bf16(af[i], bfr[j], acc[i][j], 0, 0, 0);
    }
    __syncthreads();   // all reads done before next-tile overwrite
  }

  // epilogue: C element [r0+i*16+t][c0+j*16]; lane: col=lane&15, rows=(lane>>4)*4+t
  const int r0 = mBase + wm + lk * 4;
  const int c0 = nBase + wn + l15;
#pragma unroll
  for (int i = 0; i < 4; ++i) {
#pragma unroll
    for (int j = 0; j < 2; ++j) {
      const int col = c0 + j * 16;
      float kp = (MODE == 0) ? kpm[b * SLEN + col] : 0.0f;
#pragma unroll
      for (int t = 0; t < 4; ++t) {
        const int row = r0 + i * 16 + t;
        if (MODE == 0) {
          float sc = acc[i][j][t] * (1.0f / DDIM);
          if (kp == 0.0f || mm[(size_t)row * SLEN + col] == 0.0f) sc = NEGV;
          outb[(size_t)b * M * N + (size_t)row * N + col] = f2bf(sc);
        } else {
          const size_t idx = (size_t)b * M * N + (size_t)row * N + col;
          outf[idx] = acc[i][j][t] + resid[idx];
        }
      }
    }
  }
}

// ---------------------------------------------------------------- kernel 4
// Row softmax over S=2048 bf16 values, in place. grid B*S, block 256.
__global__ __launch_bounds__(256)
void softmax_rows(u16* __restrict__ sc) {
  u16* p = sc + (size_t)blockIdx.x * SLEN;
  const int tid = threadIdx.x;
  uint4 raw = ((const uint4*)p)[tid];
  u16* rp = (u16*)&raw;
  float v[8];
#pragma unroll
  for (int i = 0; i < 8; ++i) v[i] = bf2f(rp[i]);
  float mx = v[0];
#pragma unroll
  for (int i = 1; i < 8; ++i) mx = fmaxf(mx, v[i]);
  mx = wred_max(mx);
  __shared__ float redm[4], reds[4];
  const int wid = tid >> 6, lane = tid & 63;
  if (lane == 0) redm[wid] = mx;
  __syncthreads();
  mx = fmaxf(fmaxf(redm[0], redm[1]), fmaxf(redm[2], redm[3]));
  float e[8], s = 0.0f;
#pragma unroll
  for (int i = 0; i < 8; ++i) { e[i] = __expf(v[i] - mx); s += e[i]; }
  s = wred_sum(s);
  if (lane == 0) reds[wid] = s;
  __syncthreads();
  s = reds[0] + reds[1] + reds[2] + reds[3];
  const float inv = 1.0f / s;
#pragma unroll
  for (int i = 0; i < 8; ++i) rp[i] = f2bf(e[i] * inv);
  ((uint4*)p)[tid] = raw;
}

// ---------------------------------------------------------------- kernel 6
// Final LayerNorm, fp32 in-place on d_out. grid B*S, block 256.
__global__ __launch_bounds__(256)
void ln_f32_inplace(float* __restrict__ x, const float* __restrict__ gamma,
                    const float* __restrict__ beta) {
  float* p = x + (size_t)blockIdx.x * DDIM;
  const int tid = threadIdx.x;
  float4 v = ((const float4*)p)[tid];
  float s  = v.x + v.y + v.z + v.w;
  float s2 = v.x * v.x + v.y * v.y + v.z * v.z + v.w * v.w;
  s = wred_sum(s); s2 = wred_sum(s2);
  __shared__ float rs_[4], rs2_[4];
  const int wid = tid >> 6, lane = tid & 63;
  if (lane == 0) { rs_[wid] = s; rs2_[wid] = s2; }
  __syncthreads();
  s  = rs_[0] + rs_[1] + rs_[2] + rs_[3];
  s2 = rs2_[0] + rs2_[1] + rs2_[2] + rs2_[3];
  const float mu = s * (1.0f / DDIM);
  const float var = s2 * (1.0f / DDIM) - mu * mu;
  const float rstd = rsqrtf(var + 1e-5f);
  float4 g = ((const float4*)gamma)[tid];
  float4 be = ((const float4*)beta)[tid];
  float4 o;
  o.x = (v.x - mu) * rstd * g.x + be.x;
  o.y = (v.y - mu) * rstd * g.y + be.y;
  o.z = (v.z - mu) * rstd * g.z + be.z;
  o.w = (v.w - mu) * rstd * g.w + be.w;
  ((float4*)p)[tid] = o;
}

extern "C" void kernel_launch(void* const* d_in, const int* in_sizes, int n_in,
                              void* d_out, int out_size, void* d_ws, size_t ws_size,
                              hipStream_t stream) {
  const float* src   = (const float*)d_in[0];
  const float* trg   = (const float*)d_in[1];
  const float* kpm   = (const float*)d_in[2];
  const float* mm    = (const float*)d_in[3];
  const float* gamma = (const float*)d_in[4];
  const float* beta  = (const float*)d_in[5];
  float* out = (float*)d_out;
  char* ws = (char*)d_ws;

  const size_t MB = 1024 * 1024;
  u16* src_n  = (u16*)(ws);                 // 16 MB  [B][S][D] bf16
  u16* trg_n  = (u16*)(ws + 16 * MB);       // 16 MB  [B][S][D] bf16
  u16* src_nT = (u16*)(ws + 32 * MB);       // 16 MB  [B][D][S] bf16
  u16* scores = (u16*)(ws + 48 * MB);       // 32 MB  [B][S][S] bf16

  ln_to_bf16<<<dim3(BATCH * SLEN, 2), 256, 0, stream>>>(src, trg, gamma, beta, src_n, trg_n);
  transpose_bf16<<<dim3(SLEN / 64, DDIM / 64, BATCH), 256, 0, stream>>>(src_n, src_nT);
  // scores: M=N=2048, K=1024 -> 16 x 32 tiles x 4 batches = 2048 blocks (flat)
  gemm_nt<0><<<dim3(BATCH * (SLEN / 128) * (SLEN / 64)), 256, 0, stream>>>(
      trg_n, src_n, SLEN, SLEN, DDIM, kpm, mm, scores, nullptr, nullptr);
  softmax_rows<<<dim3(BATCH * SLEN), 256, 0, stream>>>(scores);
  // PV: M=2048, N=1024, K=2048 -> 16 x 16 tiles x 4 batches = 1024 blocks (flat)
  gemm_nt<1><<<dim3(BATCH * (SLEN / 128) * (DDIM / 64)), 256, 0, stream>>>(
      scores, src_nT, SLEN, DDIM, SLEN, nullptr, nullptr, nullptr, src, out);
  ln_f32_inplace<<<dim3(BATCH * SLEN), 256, 0, stream>>>(out, gamma, beta);
}